// Round 1
// baseline (930.058 us; speedup 1.0000x reference)
//
#include <hip/hip_runtime.h>
#include <hip/hip_bf16.h>
#include <math.h>

// ---------------------------------------------------------------------------
// GauntTensorProduct: LMAX=4, C=128, COUT=128, NLM=25, B=16384
// Strategy: collapse the S2 grid analytically into the Gaunt tensor
//   G[i,i1,i2] = sum_{g,h} wq[g] Y[i,g,h] Y[i1,g,h] Y[i2,g,h]   (25^3)
// then:
//   kern[b,i2]   = sh[b,i2] * w2[l(i2)]
//   M[b,i,i1]    = sum_i2 G[i,i1,i2] kern[b,i2]
//   image[b,c,i1]= feature_blocked[b,c,i1] * w1[c,l(i1)]
//   feat[b,c,i]  = sum_i1 image[b,c,i1] M[b,i,i1]
//   out[b, 128*l^2 + a*(2l+1)+j] = sum_c feat[b,c,l^2+j] wc[l,c,a]
// Y / wq / G are computed on device every launch (graph-safe, same work).
// ---------------------------------------------------------------------------

#define NB_TOTAL 16384
#define NLM 25
#define CCH 128

__constant__ int LTAB[25] = {0, 1,1,1, 2,2,2,2,2, 3,3,3,3,3,3,3, 4,4,4,4,4,4,4,4,4};
__constant__ double FACT[9] = {1.0,1.0,2.0,6.0,24.0,120.0,720.0,5040.0,40320.0};

#define PI_D 3.14159265358979323846

// --- K0: 16-point Gauss-Legendre nodes + (weights * 2pi/15) in double -------
__global__ void k_nodes(double* __restrict__ XG, double* __restrict__ WG) {
    int g = threadIdx.x;
    if (g >= 16) return;
    double x = cos(PI_D * (g + 0.75) / 16.5);
    for (int it = 0; it < 40; ++it) {
        double p0 = 1.0, p1 = x;
        for (int k = 2; k <= 16; ++k) {
            double pk = ((2.0 * k - 1.0) * x * p1 - (k - 1.0) * p0) / k;
            p0 = p1; p1 = pk;
        }
        double dp = 16.0 * (x * p1 - p0) / (x * x - 1.0);
        x -= p1 / dp;
    }
    double p0 = 1.0, p1 = x;
    for (int k = 2; k <= 16; ++k) {
        double pk = ((2.0 * k - 1.0) * x * p1 - (k - 1.0) * p0) / k;
        p0 = p1; p1 = pk;
    }
    double dp = 16.0 * (x * p1 - p0) / (x * x - 1.0);
    XG[g] = x;
    WG[g] = 2.0 / ((1.0 - x * x) * dp * dp) * (2.0 * PI_D / 15.0);
}

// --- K1: real spherical harmonics on the grid, Y[i][g][h], i<25,g<16,h<15 ---
__global__ void k_ylm(const double* __restrict__ XG, float* __restrict__ Y) {
    int i = blockIdx.x;
    int t = threadIdx.x;
    if (t >= 240) return;
    int g = t / 15, h = t % 15;
    int l = LTAB[i];
    int m = i - l * l - l;
    int am = m < 0 ? -m : m;
    double x = XG[g];
    double s = sqrt(fmax(0.0, 1.0 - x * x));
    double P[5][5];
    P[0][0] = 1.0;
    for (int mm = 1; mm <= 4; ++mm) P[mm][mm] = -(2.0 * mm - 1.0) * s * P[mm - 1][mm - 1];
    for (int mm = 0; mm < 4; ++mm)  P[mm + 1][mm] = (2.0 * mm + 1.0) * x * P[mm][mm];
    for (int mm = 0; mm <= 4; ++mm)
        for (int ll = mm + 2; ll <= 4; ++ll)
            P[ll][mm] = ((2.0 * ll - 1.0) * x * P[ll - 1][mm] - (ll + mm - 1.0) * P[ll - 2][mm]) / (ll - mm);
    double K = sqrt((2.0 * l + 1.0) / (4.0 * PI_D) * FACT[l - am] / FACT[l + am]);
    double alpha = 2.0 * PI_D * h / 15.0;
    double v;
    if (m == 0)      v = K * P[l][0];
    else if (m > 0)  v = sqrt(2.0) * K * P[l][am] * cos(am * alpha);
    else             v = sqrt(2.0) * K * P[l][am] * sin(am * alpha);
    Y[i * 240 + g * 15 + h] = (float)v;
}

// --- K2: Gaunt tensor G[i][i1][i2] (25^3 = 15625 floats) --------------------
__global__ void k_gaunt(const float* __restrict__ Y, const double* __restrict__ WG,
                        float* __restrict__ G) {
    int t = blockIdx.x * 256 + threadIdx.x;
    if (t >= 15625) return;
    int i  = t / 625;
    int r  = t % 625;
    int i1 = r / 25;
    int i2 = r % 25;
    const float* y0 = Y + i  * 240;
    const float* y1 = Y + i1 * 240;
    const float* y2 = Y + i2 * 240;
    double acc = 0.0;
    for (int g = 0; g < 16; ++g) {
        double shs = 0.0;
        for (int h = 0; h < 15; ++h) {
            int o = g * 15 + h;
            shs += (double)y0[o] * (double)y1[o] * (double)y2[o];
        }
        acc += WG[g] * shs;
    }
    G[t] = (float)acc;
}

// --- K3: M[b][i][i1] = sum_i2 G[i][i1][i2] * sh[b,i2]*w2[l(i2)], NB=8/block -
__global__ __launch_bounds__(256) void k_M(const float* __restrict__ sh,
                                           const float* __restrict__ w2,
                                           const float* __restrict__ G,
                                           float* __restrict__ M) {
    __shared__ float Gs[15625];
    __shared__ float kerns[8 * 25];
    int tid = threadIdx.x;
    int b0 = blockIdx.x * 8;
    for (int t = tid; t < 15625; t += 256) Gs[t] = G[t];
    if (tid < 200) {
        int nb = tid / 25, ii = tid % 25;
        kerns[tid] = sh[(size_t)(b0 + nb) * 25 + ii] * w2[LTAB[ii]];
    }
    __syncthreads();
    for (int e = tid; e < 8 * 625; e += 256) {
        int nb = e / 625;
        int r  = e % 625;          // r = i*25 + i1
        const float* gr = &Gs[r * 25];
        const float* kr = &kerns[nb * 25];
        float acc = 0.0f;
#pragma unroll
        for (int i2 = 0; i2 < 25; ++i2) acc = fmaf(gr[i2], kr[i2], acc);
        M[(size_t)(b0 + nb) * 625 + r] = acc;
    }
}

// --- K4: feat[i][b][c] = sum_i1 image[b,c,i1] * M[b,i,i1] -------------------
__global__ __launch_bounds__(256) void k_feat(const float* __restrict__ feature,
                                              const float* __restrict__ w1,
                                              const float* __restrict__ M,
                                              float* __restrict__ feat) {
    int b = blockIdx.x;
    int tid = threadIdx.x;
    __shared__ float img[3200];   // [c][i1], stride 25
    __shared__ float Ms[625];
    __shared__ float w1s[640];
    for (int t = tid; t < 640; t += 256) w1s[t] = w1[t];
    for (int t = tid; t < 625; t += 256) Ms[t] = M[(size_t)b * 625 + t];
    const float* frow = feature + (size_t)b * 3200;
    // stage blocked feature -> img[c*25 + i], applying w1
    for (int e = tid; e < 128; e += 256) {                       // l=0, d=1
        img[e * 25 + 0] = frow[e] * w1s[e * 5 + 0];
    }
    for (int e = tid; e < 384; e += 256) {                       // l=1, d=3
        int c = e / 3, j = e - c * 3;
        img[c * 25 + 1 + j] = frow[128 + e] * w1s[c * 5 + 1];
    }
    for (int e = tid; e < 640; e += 256) {                       // l=2, d=5
        int c = e / 5, j = e - c * 5;
        img[c * 25 + 4 + j] = frow[512 + e] * w1s[c * 5 + 2];
    }
    for (int e = tid; e < 896; e += 256) {                       // l=3, d=7
        int c = e / 7, j = e - c * 7;
        img[c * 25 + 9 + j] = frow[1152 + e] * w1s[c * 5 + 3];
    }
    for (int e = tid; e < 1152; e += 256) {                      // l=4, d=9
        int c = e / 9, j = e - c * 9;
        img[c * 25 + 16 + j] = frow[2048 + e] * w1s[c * 5 + 4];
    }
    __syncthreads();
    for (int e = tid; e < 3200; e += 256) {
        int i = e >> 7;          // wave-uniform
        int c = e & 127;
        const float* mr = &Ms[i * 25];
        const float* ir = &img[c * 25];
        float acc = 0.0f;
#pragma unroll
        for (int i1 = 0; i1 < 25; ++i1) acc = fmaf(ir[i1], mr[i1], acc);
        feat[(size_t)i * (NB_TOTAL * 128) + (size_t)b * 128 + c] = acc;
    }
}

// --- K5: out GEMMs. grid=(256 btiles, 25 i). Tile: 64b x 128a, K=128 --------
__global__ __launch_bounds__(256) void k_out(const float* __restrict__ feat,
                                             const float* __restrict__ wc,
                                             float* __restrict__ out) {
    int i = blockIdx.y;
    int l = LTAB[i];
    int j = i - l * l;
    int d = 2 * l + 1;
    int btile = blockIdx.x * 64;
    int tid = threadIdx.x;
    int tx = tid & 15;     // a-group: a = tx*8 .. tx*8+7
    int ty = tid >> 4;     // b-group: b = ty*4 .. ty*4+3
    __shared__ float As[32 * 68];    // [k][bm], stride 68 (16B-aligned, bank-rotating)
    __shared__ float Ws[32 * 128];   // [k][a]
    const float* fi = feat + (size_t)i * (NB_TOTAL * 128) + (size_t)btile * 128;
    const float* wl = wc + l * 16384;
    float acc[4][8];
#pragma unroll
    for (int m = 0; m < 4; ++m)
#pragma unroll
        for (int n = 0; n < 8; ++n) acc[m][n] = 0.0f;

    for (int k0 = 0; k0 < 128; k0 += 32) {
#pragma unroll
        for (int p = 0; p < 8; ++p) {           // A: 64x32
            int idx = tid + p * 256;
            int bm = idx >> 5, kk = idx & 31;
            As[kk * 68 + bm] = fi[(size_t)bm * 128 + k0 + kk];
        }
#pragma unroll
        for (int p = 0; p < 16; ++p) {          // W: 32x128
            int idx = tid + p * 256;
            int kk = idx >> 7, a = idx & 127;
            Ws[kk * 128 + a] = wl[(size_t)(k0 + kk) * 128 + a];
        }
        __syncthreads();
#pragma unroll
        for (int k = 0; k < 32; ++k) {
            const float4 af = *(const float4*)&As[k * 68 + ty * 4];
            const float4 wa = *(const float4*)&Ws[k * 128 + tx * 8];
            const float4 wb = *(const float4*)&Ws[k * 128 + tx * 8 + 4];
            float av[4] = {af.x, af.y, af.z, af.w};
            float wv[8] = {wa.x, wa.y, wa.z, wa.w, wb.x, wb.y, wb.z, wb.w};
#pragma unroll
            for (int m = 0; m < 4; ++m)
#pragma unroll
                for (int n = 0; n < 8; ++n)
                    acc[m][n] = fmaf(av[m], wv[n], acc[m][n]);
        }
        __syncthreads();
    }
    int offl = 128 * l * l;
#pragma unroll
    for (int m = 0; m < 4; ++m) {
        int b = btile + ty * 4 + m;
        float* orow = out + (size_t)b * 3200 + offl + j;
#pragma unroll
        for (int n = 0; n < 8; ++n) {
            orow[(size_t)(tx * 8 + n) * d] = acc[m][n];
        }
    }
}

extern "C" void kernel_launch(void* const* d_in, const int* in_sizes, int n_in,
                              void* d_out, int out_size, void* d_ws, size_t ws_size,
                              hipStream_t stream) {
    const float* feature = (const float*)d_in[0];   // (16384, 3200)
    const float* sh      = (const float*)d_in[1];   // (16384, 25)
    const float* w1      = (const float*)d_in[2];   // (128, 5)
    const float* w2      = (const float*)d_in[3];   // (5,)
    const float* wc      = (const float*)d_in[4];   // (5, 128, 128)
    float* out = (float*)d_out;                     // (16384, 3200)

    char* w = (char*)d_ws;
    double* XG = (double*)(w + 0);                  // 16 doubles
    double* WG = (double*)(w + 128);                // 16 doubles
    float*  Yf = (float*)(w + 256);                 // 25*240 = 6000 f
    float*  Gf = (float*)(w + 24320);               // 15625 f
    float*  Mf = (float*)(w + 87040);               // 16384*625 f = 40.96 MB
    float*  Ff = (float*)(w + 41047040ULL);         // 25*16384*128 f = 209.7 MB

    hipLaunchKernelGGL(k_nodes, dim3(1),   dim3(64),  0, stream, XG, WG);
    hipLaunchKernelGGL(k_ylm,   dim3(25),  dim3(256), 0, stream, XG, Yf);
    hipLaunchKernelGGL(k_gaunt, dim3(62),  dim3(256), 0, stream, Yf, WG, Gf);
    hipLaunchKernelGGL(k_M,     dim3(2048),dim3(256), 0, stream, sh, w2, Gf, Mf);
    hipLaunchKernelGGL(k_feat,  dim3(16384), dim3(256), 0, stream, feature, w1, Mf, Ff);
    hipLaunchKernelGGL(k_out,   dim3(256, 25), dim3(256), 0, stream, Ff, wc, out);
}

// Round 2
// 817.090 us; speedup vs baseline: 1.1383x; 1.1383x over previous
//
#include <hip/hip_runtime.h>
#include <hip/hip_bf16.h>
#include <math.h>

// ---------------------------------------------------------------------------
// GauntTensorProduct: LMAX=4, C=128, COUT=128, NLM=25, B=16384
//   G[i,i1,i2] = sum_{g,h} wq[g] Y[i,g,h] Y[i1,g,h] Y[i2,g,h]   (25^3, exact)
//   M[b,i,i1]  = sum_i2 G[i,i1,i2] sh[b,i2] w2[l(i2)]
//   feat[i,b,c]= sum_i1 feature_blk[b,c,i1] w1[c,l(i1)] M[b,i,i1]   (bf16)
//   out[b, 128 l^2 + a(2l+1)+j] = sum_c feat[l^2+j,b,c] wc[l,c,a]   (MFMA)
// ---------------------------------------------------------------------------

#define NB_TOTAL 16384
#define PLANE ((size_t)NB_TOTAL * 128)

typedef __attribute__((ext_vector_type(8))) short bf16x8;
typedef __attribute__((ext_vector_type(4))) float f32x4;
typedef unsigned short u16;

__constant__ int LTAB[25] = {0, 1,1,1, 2,2,2,2,2, 3,3,3,3,3,3,3, 4,4,4,4,4,4,4,4,4};
__constant__ double FACT[9] = {1.0,1.0,2.0,6.0,24.0,120.0,720.0,5040.0,40320.0};

#define PI_D 3.14159265358979323846

__device__ inline u16 f2bf(float x) {
    __hip_bfloat16 h = __float2bfloat16(x);
    return *reinterpret_cast<u16*>(&h);
}

// --- K0: 16-point Gauss-Legendre nodes + (weights * 2pi/15) in double -------
__global__ void k_nodes(double* __restrict__ XG, double* __restrict__ WG) {
    int g = threadIdx.x;
    if (g >= 16) return;
    double x = cos(PI_D * (g + 0.75) / 16.5);
    for (int it = 0; it < 40; ++it) {
        double p0 = 1.0, p1 = x;
        for (int k = 2; k <= 16; ++k) {
            double pk = ((2.0 * k - 1.0) * x * p1 - (k - 1.0) * p0) / k;
            p0 = p1; p1 = pk;
        }
        double dp = 16.0 * (x * p1 - p0) / (x * x - 1.0);
        x -= p1 / dp;
    }
    double p0 = 1.0, p1 = x;
    for (int k = 2; k <= 16; ++k) {
        double pk = ((2.0 * k - 1.0) * x * p1 - (k - 1.0) * p0) / k;
        p0 = p1; p1 = pk;
    }
    double dp = 16.0 * (x * p1 - p0) / (x * x - 1.0);
    XG[g] = x;
    WG[g] = 2.0 / ((1.0 - x * x) * dp * dp) * (2.0 * PI_D / 15.0);
}

// --- K1: real spherical harmonics on the grid, Y[i][g][h] -------------------
__global__ void k_ylm(const double* __restrict__ XG, float* __restrict__ Y) {
    int i = blockIdx.x;
    int t = threadIdx.x;
    if (t >= 240) return;
    int g = t / 15, h = t % 15;
    int l = LTAB[i];
    int m = i - l * l - l;
    int am = m < 0 ? -m : m;
    double x = XG[g];
    double s = sqrt(fmax(0.0, 1.0 - x * x));
    double P[5][5];
    P[0][0] = 1.0;
    for (int mm = 1; mm <= 4; ++mm) P[mm][mm] = -(2.0 * mm - 1.0) * s * P[mm - 1][mm - 1];
    for (int mm = 0; mm < 4; ++mm)  P[mm + 1][mm] = (2.0 * mm + 1.0) * x * P[mm][mm];
    for (int mm = 0; mm <= 4; ++mm)
        for (int ll = mm + 2; ll <= 4; ++ll)
            P[ll][mm] = ((2.0 * ll - 1.0) * x * P[ll - 1][mm] - (ll + mm - 1.0) * P[ll - 2][mm]) / (ll - mm);
    double K = sqrt((2.0 * l + 1.0) / (4.0 * PI_D) * FACT[l - am] / FACT[l + am]);
    double alpha = 2.0 * PI_D * h / 15.0;
    double v;
    if (m == 0)      v = K * P[l][0];
    else if (m > 0)  v = sqrt(2.0) * K * P[l][am] * cos(am * alpha);
    else             v = sqrt(2.0) * K * P[l][am] * sin(am * alpha);
    Y[i * 240 + g * 15 + h] = (float)v;
}

// --- K2: Gaunt tensor G[i][i1][i2] ------------------------------------------
__global__ void k_gaunt(const float* __restrict__ Y, const double* __restrict__ WG,
                        float* __restrict__ G) {
    int t = blockIdx.x * 256 + threadIdx.x;
    if (t >= 15625) return;
    int i  = t / 625;
    int r  = t % 625;
    int i1 = r / 25;
    int i2 = r % 25;
    const float* y0 = Y + i  * 240;
    const float* y1 = Y + i1 * 240;
    const float* y2 = Y + i2 * 240;
    double acc = 0.0;
    for (int g = 0; g < 16; ++g) {
        double shs = 0.0;
        for (int h = 0; h < 15; ++h) {
            int o = g * 15 + h;
            shs += (double)y0[o] * (double)y1[o] * (double)y2[o];
        }
        acc += WG[g] * shs;
    }
    G[t] = (float)acc;
}

// --- K2b: transpose wc -> wcT bf16 [l][a][c] --------------------------------
__global__ void k_wcT(const float* __restrict__ wc, u16* __restrict__ wcT) {
    int idx = blockIdx.x * 256 + threadIdx.x;   // 81920 total
    if (idx >= 81920) return;
    int l = idx >> 14;
    int r = idx & 16383;
    int c = r >> 7;
    int a = r & 127;
    wcT[(l << 14) + (a << 7) + c] = f2bf(wc[idx]);
}

// --- K3: M[b][i*25+i1] = sum_i2 G[i,i1,i2] * sh[b,i2]*w2[l(i2)] -------------
__global__ __launch_bounds__(256) void k_M(const float* __restrict__ sh,
                                           const float* __restrict__ w2,
                                           const float* __restrict__ G,
                                           float* __restrict__ M) {
    __shared__ float Gs[15625];
    __shared__ float kerns[8 * 25];
    int tid = threadIdx.x;
    int b0 = blockIdx.x * 8;
    for (int t = tid; t < 15625; t += 256) Gs[t] = G[t];
    if (tid < 200) {
        int nb = tid / 25, ii = tid % 25;
        kerns[tid] = sh[(size_t)(b0 + nb) * 25 + ii] * w2[LTAB[ii]];
    }
    __syncthreads();
    for (int e = tid; e < 8 * 625; e += 256) {
        int nb = e / 625;
        int r  = e % 625;
        const float* gr = &Gs[r * 25];
        const float* kr = &kerns[nb * 25];
        float acc = 0.0f;
#pragma unroll
        for (int i2 = 0; i2 < 25; ++i2) acc = fmaf(gr[i2], kr[i2], acc);
        M[(size_t)(b0 + nb) * 625 + r] = acc;
    }
}

// --- K4: feat[i][b][c] (bf16) -----------------------------------------------
// lane owns (b,c): 25 feature loads -> regs, M[b] via wave-uniform s_loads.
__global__ __launch_bounds__(256) void k_feat(const float* __restrict__ feature,
                                              const float* __restrict__ w1,
                                              const float* __restrict__ M,
                                              u16* __restrict__ feat) {
    int tid = threadIdx.x;
    int wave = tid >> 6, lane = tid & 63;
    int b = blockIdx.x * 2 + (wave >> 1);
    int c = ((wave & 1) << 6) + lane;
    const float* frow = feature + (size_t)b * 3200;
    float img[25];
    {
        float wl0 = w1[c * 5 + 0];
        img[0] = frow[c] * wl0;
        float wl1 = w1[c * 5 + 1];
#pragma unroll
        for (int j = 0; j < 3; ++j) img[1 + j] = frow[128 + c * 3 + j] * wl1;
        float wl2 = w1[c * 5 + 2];
#pragma unroll
        for (int j = 0; j < 5; ++j) img[4 + j] = frow[512 + c * 5 + j] * wl2;
        float wl3 = w1[c * 5 + 3];
#pragma unroll
        for (int j = 0; j < 7; ++j) img[9 + j] = frow[1152 + c * 7 + j] * wl3;
        float wl4 = w1[c * 5 + 4];
#pragma unroll
        for (int j = 0; j < 9; ++j) img[16 + j] = frow[2048 + c * 9 + j] * wl4;
    }
    int bu = __builtin_amdgcn_readfirstlane(b);
    const float* Mb = M + (size_t)bu * 625;
    u16* fo = feat + (size_t)b * 128 + c;
#pragma unroll
    for (int i = 0; i < 25; ++i) {
        float acc = 0.0f;
#pragma unroll
        for (int i1 = 0; i1 < 25; ++i1) acc = fmaf(img[i1], Mb[i * 25 + i1], acc);
        fo[(size_t)i * PLANE] = f2bf(acc);
    }
}

// --- K5: out GEMM, MFMA bf16. Block owns (64-b-tile, l), loops j ------------
// W fragments (full K=128, all 8 n-tiles) hoisted to registers once.
// Strided 4B stores, but all d stripes of each line come from this block ->
// L2 merges -> ~1x HBM write-out.
__global__ __launch_bounds__(256) void k_out(const u16* __restrict__ feat,
                                             const u16* __restrict__ wcT,
                                             float* __restrict__ out) {
    __shared__ u16 Wt[128 * 136];   // [a][k] pad 136
    __shared__ u16 At[64 * 136];    // [b][k] pad 136
    int lin = blockIdx.x;           // 1280 = 256 btiles x 5 l, l fastest
    int l = lin % 5;
    int btile = (lin / 5) << 6;
    int d = 2 * l + 1;
    int tid = threadIdx.x;
    int wave = tid >> 6, lane = tid & 63;
    int col = lane & 15, quad = lane >> 4;

    // stage Wt[a][k] <- wcT[l][a][k]
    const u16* wl = wcT + (l << 14);
#pragma unroll
    for (int p = 0; p < 16; ++p) {
        int idx4 = tid + (p << 8);
        int a = idx4 >> 5;
        int k4 = (idx4 & 31) << 2;
        *(ushort4*)&Wt[a * 136 + k4] = *(const ushort4*)&wl[a * 128 + k4];
    }
    __syncthreads();

    // hoist all W fragments: B[k][n], lane holds col n=col, k = ks*32+quad*8+e
    bf16x8 Wf[8][4];
#pragma unroll
    for (int nt = 0; nt < 8; ++nt)
#pragma unroll
        for (int ks = 0; ks < 4; ++ks)
            Wf[nt][ks] = *(const bf16x8*)&Wt[(nt * 16 + col) * 136 + ks * 32 + (quad << 3)];

    const u16* fbase = feat + (size_t)(l * l) * PLANE + (size_t)btile * 128;

    for (int j = 0; j < d; ++j) {
        const u16* fj = fbase + (size_t)j * PLANE;
#pragma unroll
        for (int p = 0; p < 8; ++p) {
            int idx4 = tid + (p << 8);
            int r = idx4 >> 5;
            int k4 = (idx4 & 31) << 2;
            *(ushort4*)&At[r * 136 + k4] = *(const ushort4*)&fj[r * 128 + k4];
        }
        __syncthreads();

        f32x4 acc[8];
#pragma unroll
        for (int nt = 0; nt < 8; ++nt) acc[nt] = (f32x4){0.f, 0.f, 0.f, 0.f};
#pragma unroll
        for (int ks = 0; ks < 4; ++ks) {
            bf16x8 Af = *(const bf16x8*)&At[((wave << 4) + col) * 136 + ks * 32 + (quad << 3)];
#pragma unroll
            for (int nt = 0; nt < 8; ++nt)
                acc[nt] = __builtin_amdgcn_mfma_f32_16x16x32_bf16(Af, Wf[nt][ks], acc[nt], 0, 0, 0);
        }

        // C layout: col = lane&15 (=a within tile), row = quad*4 + reg (=b)
#pragma unroll
        for (int rg = 0; rg < 4; ++rg) {
            int b = btile + (wave << 4) + (quad << 2) + rg;
            float* orow = out + (size_t)b * 3200 + 128 * l * l;
#pragma unroll
            for (int nt = 0; nt < 8; ++nt) {
                int a = (nt << 4) + col;
                orow[a * d + j] = acc[nt][rg];
            }
        }
        __syncthreads();
    }
}

extern "C" void kernel_launch(void* const* d_in, const int* in_sizes, int n_in,
                              void* d_out, int out_size, void* d_ws, size_t ws_size,
                              hipStream_t stream) {
    const float* feature = (const float*)d_in[0];   // (16384, 3200)
    const float* sh      = (const float*)d_in[1];   // (16384, 25)
    const float* w1      = (const float*)d_in[2];   // (128, 5)
    const float* w2      = (const float*)d_in[3];   // (5,)
    const float* wc      = (const float*)d_in[4];   // (5, 128, 128)
    float* out = (float*)d_out;                     // (16384, 3200)

    char* w = (char*)d_ws;
    double* XG  = (double*)(w + 0);                  // 16 d
    double* WG  = (double*)(w + 128);                // 16 d
    float*  Yf  = (float*)(w + 256);                 // 6000 f -> ends 24256
    float*  Gf  = (float*)(w + 24320);               // 15625 f -> ends 86820
    u16*    WcT = (u16*)(w + 86912);                 // 81920 u16 -> ends 250752
    float*  Mf  = (float*)(w + 250880);              // 16384*625 f = 40.96 MB
    u16*    Ff  = (u16*)(w + 41210880ULL);           // 25*16384*128 u16 = 104.9 MB

    hipLaunchKernelGGL(k_nodes, dim3(1),    dim3(64),  0, stream, XG, WG);
    hipLaunchKernelGGL(k_ylm,   dim3(25),   dim3(256), 0, stream, XG, Yf);
    hipLaunchKernelGGL(k_gaunt, dim3(62),   dim3(256), 0, stream, Yf, WG, Gf);
    hipLaunchKernelGGL(k_wcT,   dim3(320),  dim3(256), 0, stream, wc, WcT);
    hipLaunchKernelGGL(k_M,     dim3(2048), dim3(256), 0, stream, sh, w2, Gf, Mf);
    hipLaunchKernelGGL(k_feat,  dim3(8192), dim3(256), 0, stream, feature, w1, Mf, Ff);
    hipLaunchKernelGGL(k_out,   dim3(1280), dim3(256), 0, stream, Ff, WcT, out);
}

// Round 3
// 561.746 us; speedup vs baseline: 1.6557x; 1.4546x over previous
//
#include <hip/hip_runtime.h>
#include <hip/hip_bf16.h>
#include <math.h>

// ---------------------------------------------------------------------------
// GauntTensorProduct: LMAX=4, C=128, COUT=128, NLM=25, B=16384
//   G[i,i1,i2] = sum_{g,h} wq[g] Y[i,g,h] Y[i1,g,h] Y[i2,g,h]   (25^3, exact)
//   M[b,i,i1]  = sum_i2 G[i,i1,i2] sh[b,i2] w2[l(i2)]
//   feat[i,b,c]= sum_i1 feature_blk[b,c,i1] w1[c,l(i1)] M[b,i,i1]   (bf16)
//   out[b, 128 l^2 + a(2l+1)+j] = sum_c feat[l^2+j,b,c] wc[l,c,a]   (MFMA)
// R3: k_out holds all j in regs -> contiguous per-lane d-float runs
//     (kills 6.6x write amplification); k_feat reads M via LDS broadcast
//     b128 (kills the 625-same-address global-load pathology).
// ---------------------------------------------------------------------------

#define NB_TOTAL 16384
#define PLANE ((size_t)NB_TOTAL * 128)

typedef __attribute__((ext_vector_type(8))) short bf16x8;
typedef __attribute__((ext_vector_type(4))) float f32x4;
typedef unsigned short u16;

__constant__ int LTAB[25] = {0, 1,1,1, 2,2,2,2,2, 3,3,3,3,3,3,3, 4,4,4,4,4,4,4,4,4};
__constant__ double FACT[9] = {1.0,1.0,2.0,6.0,24.0,120.0,720.0,5040.0,40320.0};

#define PI_D 3.14159265358979323846

__device__ inline u16 f2bf(float x) {
    __hip_bfloat16 h = __float2bfloat16(x);
    return *reinterpret_cast<u16*>(&h);
}

// --- K0: 16-point Gauss-Legendre nodes + (weights * 2pi/15) in double -------
__global__ void k_nodes(double* __restrict__ XG, double* __restrict__ WG) {
    int g = threadIdx.x;
    if (g >= 16) return;
    double x = cos(PI_D * (g + 0.75) / 16.5);
    for (int it = 0; it < 40; ++it) {
        double p0 = 1.0, p1 = x;
        for (int k = 2; k <= 16; ++k) {
            double pk = ((2.0 * k - 1.0) * x * p1 - (k - 1.0) * p0) / k;
            p0 = p1; p1 = pk;
        }
        double dp = 16.0 * (x * p1 - p0) / (x * x - 1.0);
        x -= p1 / dp;
    }
    double p0 = 1.0, p1 = x;
    for (int k = 2; k <= 16; ++k) {
        double pk = ((2.0 * k - 1.0) * x * p1 - (k - 1.0) * p0) / k;
        p0 = p1; p1 = pk;
    }
    double dp = 16.0 * (x * p1 - p0) / (x * x - 1.0);
    XG[g] = x;
    WG[g] = 2.0 / ((1.0 - x * x) * dp * dp) * (2.0 * PI_D / 15.0);
}

// --- K1: real spherical harmonics on the grid, Y[i][g][h] -------------------
__global__ void k_ylm(const double* __restrict__ XG, float* __restrict__ Y) {
    int i = blockIdx.x;
    int t = threadIdx.x;
    if (t >= 240) return;
    int g = t / 15, h = t % 15;
    int l = LTAB[i];
    int m = i - l * l - l;
    int am = m < 0 ? -m : m;
    double x = XG[g];
    double s = sqrt(fmax(0.0, 1.0 - x * x));
    double P[5][5];
    P[0][0] = 1.0;
    for (int mm = 1; mm <= 4; ++mm) P[mm][mm] = -(2.0 * mm - 1.0) * s * P[mm - 1][mm - 1];
    for (int mm = 0; mm < 4; ++mm)  P[mm + 1][mm] = (2.0 * mm + 1.0) * x * P[mm][mm];
    for (int mm = 0; mm <= 4; ++mm)
        for (int ll = mm + 2; ll <= 4; ++ll)
            P[ll][mm] = ((2.0 * ll - 1.0) * x * P[ll - 1][mm] - (ll + mm - 1.0) * P[ll - 2][mm]) / (ll - mm);
    double K = sqrt((2.0 * l + 1.0) / (4.0 * PI_D) * FACT[l - am] / FACT[l + am]);
    double alpha = 2.0 * PI_D * h / 15.0;
    double v;
    if (m == 0)      v = K * P[l][0];
    else if (m > 0)  v = sqrt(2.0) * K * P[l][am] * cos(am * alpha);
    else             v = sqrt(2.0) * K * P[l][am] * sin(am * alpha);
    Y[i * 240 + g * 15 + h] = (float)v;
}

// --- K2: Gaunt tensor G[i][i1][i2] ------------------------------------------
__global__ void k_gaunt(const float* __restrict__ Y, const double* __restrict__ WG,
                        float* __restrict__ G) {
    int t = blockIdx.x * 256 + threadIdx.x;
    if (t >= 15625) return;
    int i  = t / 625;
    int r  = t % 625;
    int i1 = r / 25;
    int i2 = r % 25;
    const float* y0 = Y + i  * 240;
    const float* y1 = Y + i1 * 240;
    const float* y2 = Y + i2 * 240;
    double acc = 0.0;
    for (int g = 0; g < 16; ++g) {
        double shs = 0.0;
        for (int h = 0; h < 15; ++h) {
            int o = g * 15 + h;
            shs += (double)y0[o] * (double)y1[o] * (double)y2[o];
        }
        acc += WG[g] * shs;
    }
    G[t] = (float)acc;
}

// --- K2b: transpose wc -> wcT bf16 [l][a][c] --------------------------------
__global__ void k_wcT(const float* __restrict__ wc, u16* __restrict__ wcT) {
    int idx = blockIdx.x * 256 + threadIdx.x;   // 81920 total
    if (idx >= 81920) return;
    int l = idx >> 14;
    int r = idx & 16383;
    int c = r >> 7;
    int a = r & 127;
    wcT[(l << 14) + (a << 7) + c] = f2bf(wc[idx]);
}

// --- K3: M[b][i*25+i1] = sum_i2 G[i,i1,i2] * sh[b,i2]*w2[l(i2)] -------------
__global__ __launch_bounds__(256) void k_M(const float* __restrict__ sh,
                                           const float* __restrict__ w2,
                                           const float* __restrict__ G,
                                           float* __restrict__ M) {
    __shared__ float Gs[15625];
    __shared__ float kerns[8 * 25];
    int tid = threadIdx.x;
    int b0 = blockIdx.x * 8;
    for (int t = tid; t < 15625; t += 256) Gs[t] = G[t];
    if (tid < 200) {
        int nb = tid / 25, ii = tid % 25;
        kerns[tid] = sh[(size_t)(b0 + nb) * 25 + ii] * w2[LTAB[ii]];
    }
    __syncthreads();
    for (int e = tid; e < 8 * 625; e += 256) {
        int nb = e / 625;
        int r  = e % 625;
        const float* gr = &Gs[r * 25];
        const float* kr = &kerns[nb * 25];
        float acc = 0.0f;
#pragma unroll
        for (int i2 = 0; i2 < 25; ++i2) acc = fmaf(gr[i2], kr[i2], acc);
        M[(size_t)(b0 + nb) * 625 + r] = acc;
    }
}

// --- K4: feat[i][b][c] (bf16). 1 wave per b, 2 c per lane. ------------------
// M[b] staged in LDS (rows padded to 28 floats, 16B-aligned) and read as
// wave-broadcast ds_read_b128.
__global__ __launch_bounds__(256) void k_feat(const float* __restrict__ feature,
                                              const float* __restrict__ w1,
                                              const float* __restrict__ M,
                                              u16* __restrict__ feat) {
    __shared__ float Ms[4][704];       // [wave_b][i*28 + i1]
    int tid = threadIdx.x;
    int wave = tid >> 6, lane = tid & 63;
    int b0 = blockIdx.x << 2;
    for (int t = tid; t < 2500; t += 256) {
        int wb = t / 625, r = t - wb * 625;
        int i = r / 25, i1 = r - i * 25;
        Ms[wb][i * 28 + i1] = M[(size_t)(b0 + wb) * 625 + r];
    }
    __syncthreads();

    int b = b0 + wave;
    int c0 = lane, c1 = lane + 64;
    const float* frow = feature + (size_t)b * 3200;
    float img0[25], img1[25];
    {
        float wa = w1[c0 * 5 + 0], wb_ = w1[c1 * 5 + 0];
        img0[0] = frow[c0] * wa;  img1[0] = frow[c1] * wb_;
        wa = w1[c0 * 5 + 1]; wb_ = w1[c1 * 5 + 1];
#pragma unroll
        for (int j = 0; j < 3; ++j) { img0[1+j] = frow[128 + c0*3 + j] * wa;
                                      img1[1+j] = frow[128 + c1*3 + j] * wb_; }
        wa = w1[c0 * 5 + 2]; wb_ = w1[c1 * 5 + 2];
#pragma unroll
        for (int j = 0; j < 5; ++j) { img0[4+j] = frow[512 + c0*5 + j] * wa;
                                      img1[4+j] = frow[512 + c1*5 + j] * wb_; }
        wa = w1[c0 * 5 + 3]; wb_ = w1[c1 * 5 + 3];
#pragma unroll
        for (int j = 0; j < 7; ++j) { img0[9+j] = frow[1152 + c0*7 + j] * wa;
                                      img1[9+j] = frow[1152 + c1*7 + j] * wb_; }
        wa = w1[c0 * 5 + 4]; wb_ = w1[c1 * 5 + 4];
#pragma unroll
        for (int j = 0; j < 9; ++j) { img0[16+j] = frow[2048 + c0*9 + j] * wa;
                                      img1[16+j] = frow[2048 + c1*9 + j] * wb_; }
    }
    u16* fo = feat + (size_t)b * 128;
#pragma unroll
    for (int i = 0; i < 25; ++i) {
        const float* mr = &Ms[wave][i * 28];
        float a0 = 0.0f, a1 = 0.0f;
#pragma unroll
        for (int q = 0; q < 6; ++q) {
            float4 m4 = *(const float4*)&mr[q * 4];
            a0 = fmaf(img0[q*4+0], m4.x, a0);  a1 = fmaf(img1[q*4+0], m4.x, a1);
            a0 = fmaf(img0[q*4+1], m4.y, a0);  a1 = fmaf(img1[q*4+1], m4.y, a1);
            a0 = fmaf(img0[q*4+2], m4.z, a0);  a1 = fmaf(img1[q*4+2], m4.z, a1);
            a0 = fmaf(img0[q*4+3], m4.w, a0);  a1 = fmaf(img1[q*4+3], m4.w, a1);
        }
        float ml = mr[24];
        a0 = fmaf(img0[24], ml, a0);  a1 = fmaf(img1[24], ml, a1);
        fo[(size_t)i * PLANE + c0] = f2bf(a0);
        fo[(size_t)i * PLANE + c1] = f2bf(a1);
    }
}

// --- K5: out GEMM per l (templated). Block = 16 b-rows, 4 waves x 2 n-tiles.
// All j accumulated in registers; each lane ends owning contiguous d-float
// runs at out[b, 128 l^2 + a*d + (0..d-1)] -> dense stores, no write amp.
// A and W fragments loaded directly from global (16B aligned), no LDS.
template<int L>
__global__ __launch_bounds__(256) void k_out_t(const u16* __restrict__ feat,
                                               const u16* __restrict__ wcT,
                                               float* __restrict__ out) {
    constexpr int D = 2 * L + 1;
    int btile = blockIdx.x << 4;
    int tid = threadIdx.x;
    int wave = tid >> 6, lane = tid & 63;
    int col = lane & 15, quad = lane >> 4;

    const u16* wl = wcT + (L << 14);
    bf16x8 Wf[2][4];
#pragma unroll
    for (int t = 0; t < 2; ++t) {
        int a = ((wave * 2 + t) << 4) + col;
#pragma unroll
        for (int ks = 0; ks < 4; ++ks)
            Wf[t][ks] = *(const bf16x8*)&wl[a * 128 + ks * 32 + (quad << 3)];
    }

    const u16* fbase = feat + (size_t)(L * L) * PLANE
                            + (size_t)(btile + col) * 128 + (quad << 3);
    f32x4 acc[2][D];
#pragma unroll
    for (int t = 0; t < 2; ++t)
#pragma unroll
        for (int j = 0; j < D; ++j) acc[t][j] = (f32x4){0.f, 0.f, 0.f, 0.f};

#pragma unroll
    for (int j = 0; j < D; ++j) {
        const u16* fj = fbase + (size_t)j * PLANE;
#pragma unroll
        for (int ks = 0; ks < 4; ++ks) {
            bf16x8 Af = *(const bf16x8*)&fj[ks * 32];
#pragma unroll
            for (int t = 0; t < 2; ++t)
                acc[t][j] = __builtin_amdgcn_mfma_f32_16x16x32_bf16(Af, Wf[t][ks], acc[t][j], 0, 0, 0);
        }
    }

#pragma unroll
    for (int t = 0; t < 2; ++t) {
        int a = ((wave * 2 + t) << 4) + col;
#pragma unroll
        for (int rg = 0; rg < 4; ++rg) {
            int b = btile + (quad << 2) + rg;
            float* p = out + (size_t)b * 3200 + 128 * L * L + a * D;
#pragma unroll
            for (int j = 0; j < D; ++j) p[j] = acc[t][j][rg];
        }
    }
}

extern "C" void kernel_launch(void* const* d_in, const int* in_sizes, int n_in,
                              void* d_out, int out_size, void* d_ws, size_t ws_size,
                              hipStream_t stream) {
    const float* feature = (const float*)d_in[0];   // (16384, 3200)
    const float* sh      = (const float*)d_in[1];   // (16384, 25)
    const float* w1      = (const float*)d_in[2];   // (128, 5)
    const float* w2      = (const float*)d_in[3];   // (5,)
    const float* wc      = (const float*)d_in[4];   // (5, 128, 128)
    float* out = (float*)d_out;                     // (16384, 3200)

    char* w = (char*)d_ws;
    double* XG  = (double*)(w + 0);                  // 16 d
    double* WG  = (double*)(w + 128);                // 16 d
    float*  Yf  = (float*)(w + 256);                 // 6000 f
    float*  Gf  = (float*)(w + 24320);               // 15625 f
    u16*    WcT = (u16*)(w + 86912);                 // 81920 u16
    float*  Mf  = (float*)(w + 250880);              // 16384*625 f = 40.96 MB
    u16*    Ff  = (u16*)(w + 41210880ULL);           // 25*16384*128 u16 = 104.9 MB

    hipLaunchKernelGGL(k_nodes, dim3(1),    dim3(64),  0, stream, XG, WG);
    hipLaunchKernelGGL(k_ylm,   dim3(25),   dim3(256), 0, stream, XG, Yf);
    hipLaunchKernelGGL(k_gaunt, dim3(62),   dim3(256), 0, stream, Yf, WG, Gf);
    hipLaunchKernelGGL(k_wcT,   dim3(320),  dim3(256), 0, stream, wc, WcT);
    hipLaunchKernelGGL(k_M,     dim3(2048), dim3(256), 0, stream, sh, w2, Gf, Mf);
    hipLaunchKernelGGL(k_feat,  dim3(4096), dim3(256), 0, stream, feature, w1, Mf, Ff);
    hipLaunchKernelGGL(k_out_t<0>, dim3(1024), dim3(256), 0, stream, Ff, WcT, out);
    hipLaunchKernelGGL(k_out_t<1>, dim3(1024), dim3(256), 0, stream, Ff, WcT, out);
    hipLaunchKernelGGL(k_out_t<2>, dim3(1024), dim3(256), 0, stream, Ff, WcT, out);
    hipLaunchKernelGGL(k_out_t<3>, dim3(1024), dim3(256), 0, stream, Ff, WcT, out);
    hipLaunchKernelGGL(k_out_t<4>, dim3(1024), dim3(256), 0, stream, Ff, WcT, out);
}